// Round 1
// baseline (209.127 us; speedup 1.0000x reference)
//
#include <hip/hip_runtime.h>

// Problem constants
constexpr int BATCH = 64;     // M
constexpr int IC    = 8192;   // K
constexpr int OC    = 8192;   // N
constexpr int OCH   = 4096;   // packed rows (OC/2)
constexpr int KSPLIT = 4;
constexpr int KPER  = IC / KSPLIT;   // 2048
constexpr int BK    = 128;           // K-chunk staged in LDS (doubled vs prev)
constexpr int NITER = KPER / BK;     // 16
constexpr int LDK   = BK + 8;        // 136: keeps the conflict-free bank rotation

typedef __bf16 bf16x8 __attribute__((ext_vector_type(8)));
typedef float  f32x4  __attribute__((ext_vector_type(4)));

// fp32 -> bf16 round-to-nearest-even
static __device__ __forceinline__ unsigned short f2bf(float f) {
    unsigned u = __float_as_uint(f);
    u += 0x7FFFu + ((u >> 16) & 1u);
    return (unsigned short)(u >> 16);
}

// (bf16(n1)<<16) | bf16(n0) for small ints 0..15 (fp32 truncation exact)
static __device__ __forceinline__ unsigned pack2bf(int n0, int n1) {
    unsigned f0 = __float_as_uint((float)n0);
    unsigned f1 = __float_as_uint((float)n1);
    return __builtin_amdgcn_perm(f1, f0, 0x07060302u);
}

// ---------------------------------------------------------------------------
// Prep: input fp32 [64,8192] -> bf16 in ws, plus per-row sums S[64]
// ---------------------------------------------------------------------------
__global__ __launch_bounds__(256) void prep_kernel(
    const float* __restrict__ in, unsigned short* __restrict__ Abf,
    float* __restrict__ S)
{
    const int b = blockIdx.x;
    const int t = threadIdx.x;
    const float* row = in + (size_t)b * IC;
    unsigned short* orow = Abf + (size_t)b * IC;

    float sum = 0.f;
#pragma unroll
    for (int i = 0; i < IC / 1024; ++i) {
        const int c = i * 1024 + t * 4;
        const float4 v = *(const float4*)(row + c);
        sum += (v.x + v.y) + (v.z + v.w);
        ushort4 o = make_ushort4(f2bf(v.x), f2bf(v.y), f2bf(v.z), f2bf(v.w));
        *(ushort4*)(orow + c) = o;
    }
#pragma unroll
    for (int off = 32; off > 0; off >>= 1) sum += __shfl_down(sum, off);

    __shared__ float red[4];
    if ((t & 63) == 0) red[t >> 6] = sum;
    __syncthreads();
    if (t == 0) S[b] = (red[0] + red[1]) + (red[2] + red[3]);
}

// ---------------------------------------------------------------------------
// GEMM: partial[ks][64][8192] = A.Q^T over this split's K-range.
// 512 blocks (128 n-tiles x 4 k-splits) x 512 threads (8 waves).
// Tile M=64 x N=64; BK=128 per iter, wave-quads split K halves (kh=0/1) and
// cross-reduce via LDS at the epilogue. Depth-2 register prefetch: the loads
// being staged were issued one full iteration earlier, so the vmcnt wait
// before LDS writes never targets fresh loads. One barrier per 128-K chunk.
// ---------------------------------------------------------------------------
__global__ __launch_bounds__(512, 4) void gemm_kernel(
    const unsigned short* __restrict__ Abf,   // bf16 [64][8192]
    const int* __restrict__ wp,               // packed [4096][8192]
    float* __restrict__ part)                 // fp32 [KSPLIT][64][8192]
{
    __shared__ unsigned short lA[2][64 * LDK];
    __shared__ unsigned short lW[2][64 * LDK];  // rows 0..31 lo nibble, 32..63 hi

    const int t    = threadIdx.x;
    const int lane = t & 63;
    const int lm   = lane & 15;
    const int lq   = lane >> 4;
    const int wv   = (t >> 6) & 3;   // column-wave 0..3
    const int kh   = t >> 8;         // K-half 0/1

    const int nt  = blockIdx.x & 127;
    const int ks  = blockIdx.x >> 7;
    const int r0  = nt * 32;
    const int kb0 = ks * KPER;

    f32x4 acc[4];
    const f32x4 zero4 = {0.f, 0.f, 0.f, 0.f};
#pragma unroll
    for (int i = 0; i < 4; ++i) acc[i] = zero4;

    // staging maps: A: 64 rows x 8 segs of 16 bf16; W: 32 rows x 16 segs of 8 ints
    const int uAr = t >> 3, uAc = (t & 7) * 16;
    const int uWr = t >> 4, uWc = (t & 15) * 8;

    const unsigned short* pA = Abf + (size_t)uAr * IC + kb0 + uAc;
    const int*            pW = wp  + (size_t)(r0 + uWr) * IC + kb0 + uWc;

    // LDS offsets (ushort units)
    const int sAo   = uAr * LDK + uAc;
    const int sWoLo = uWr * LDK + uWc;
    const int sWoHi = (uWr + 32) * LDK + uWc;
    const int fBo   = (wv * 16 + lm) * LDK + kh * 64 + lq * 8;
    const int fAo   = lm * LDK + kh * 64 + lq * 8;

    int4 aA0, aA1, wA0, wA1;   // register set A (even chunks)
    int4 aB0, aB1, wB0, wB1;   // register set B (odd chunks)

#define LOADG(sa0, sa1, sw0, sw1, koff)              \
    sa0 = *(const int4*)(pA + (koff));               \
    sa1 = *(const int4*)(pA + (koff) + 8);           \
    sw0 = *(const int4*)(pW + (koff));               \
    sw1 = *(const int4*)(pW + (koff) + 4);

#define STAGE(buf, sa0, sa1, sw0, sw1) {             \
    *(int4*)(&lA[buf][sAo])     = sa0;               \
    *(int4*)(&lA[buf][sAo + 8]) = sa1;               \
    int4 lo_, hi_;                                   \
    lo_.x = pack2bf(sw0.x & 15, sw0.y & 15);         \
    lo_.y = pack2bf(sw0.z & 15, sw0.w & 15);         \
    lo_.z = pack2bf(sw1.x & 15, sw1.y & 15);         \
    lo_.w = pack2bf(sw1.z & 15, sw1.w & 15);         \
    hi_.x = pack2bf(sw0.x >> 4, sw0.y >> 4);         \
    hi_.y = pack2bf(sw0.z >> 4, sw0.w >> 4);         \
    hi_.z = pack2bf(sw1.x >> 4, sw1.y >> 4);         \
    hi_.w = pack2bf(sw1.z >> 4, sw1.w >> 4);         \
    *(int4*)(&lW[buf][sWoLo]) = lo_;                 \
    *(int4*)(&lW[buf][sWoHi]) = hi_; }

#define MM(p) {                                                                   \
    _Pragma("unroll")                                                             \
    for (int s = 0; s < 2; ++s) {                                                 \
        const bf16x8 bfrg = *(const bf16x8*)(&lW[p][fBo + s * 32]);               \
        _Pragma("unroll")                                                         \
        for (int mt = 0; mt < 4; ++mt) {                                          \
            const bf16x8 afrg = *(const bf16x8*)(&lA[p][fAo + mt * 16 * LDK + s * 32]); \
            acc[mt] = __builtin_amdgcn_mfma_f32_16x16x32_bf16(afrg, bfrg, acc[mt], 0, 0, 0); \
        } } }

    // ---- prologue: chunks 0 and 1 in flight; stage chunk 0 ----
    LOADG(aA0, aA1, wA0, wA1, 0);
    LOADG(aB0, aB1, wB0, wB1, BK);
    STAGE(0, aA0, aA1, wA0, wA1);
    __syncthreads();

    // ---- main loop: 7 pairs covering it = 0..13; issues chunks 2..15 ----
    for (int it2 = 0; it2 < (NITER - 2) / 2; ++it2) {
        {   // even it: compute buf0 (chunk it), issue chunk it+2 -> setA,
            // stage chunk it+1 (setB, issued last iter) -> buf1
            const int koff = (2 * it2 + 2) * BK;
            LOADG(aA0, aA1, wA0, wA1, koff);
            MM(0);
            STAGE(1, aB0, aB1, wB0, wB1);
            __syncthreads();
        }
        {   // odd it: compute buf1, issue chunk it+2 -> setB,
            // stage chunk it+1 (setA, issued last iter) -> buf0
            const int koff = (2 * it2 + 3) * BK;
            LOADG(aB0, aB1, wB0, wB1, koff);
            MM(1);
            STAGE(0, aA0, aA1, wA0, wA1);
            __syncthreads();
        }
    }
    // it = NITER-2: compute buf0, stage chunk 15 (setB) -> buf1 (no issue)
    MM(0);
    STAGE(1, aB0, aB1, wB0, wB1);
    __syncthreads();
    // it = NITER-1: compute buf1
    MM(1);

#undef LOADG
#undef STAGE
#undef MM

    // ---- epilogue: cross-reduce kh halves via LDS, then store ----
    __syncthreads();                       // all LDS reads of lA/lW done
    f32x4* lR = (f32x4*)(&lA[0][0]);       // 16 KiB scratch
    const int o = (wv * 64 + lane) << 2;
    if (kh) {
#pragma unroll
        for (int mt = 0; mt < 4; ++mt) lR[o + mt] = acc[mt];
    }
    __syncthreads();
    if (!kh) {
#pragma unroll
        for (int mt = 0; mt < 4; ++mt) acc[mt] += lR[o + mt];

        // C/D layout: col(n) = lane&15, row(m within tile) = lq*4 + reg.
        const int cr = wv * 16 + lm;
        const int ch = (cr < 32) ? (r0 + cr) : (OCH + r0 + (cr - 32));
        float* pout = part + (size_t)ks * (BATCH * OC) + ch;

#pragma unroll
        for (int mt = 0; mt < 4; ++mt) {
#pragma unroll
            for (int r = 0; r < 4; ++r) {
                const int m = mt * 16 + lq * 4 + r;
                pout[(size_t)m * OC] = acc[mt][r];
            }
        }
    }
}

// ---------------------------------------------------------------------------
// Reduce: out[m][ch] = delta[ch]*dot + bias[ch] - delta[ch]*zp[ch]*S[m]
// Sums KSPLIT partials; fully overwrites d_out (no memset needed).
// ---------------------------------------------------------------------------
__global__ __launch_bounds__(256) void reduce_kernel(
    const float* __restrict__ part,   // [KSPLIT][64][8192]
    const float* __restrict__ delta,
    const float* __restrict__ zp,
    const float* __restrict__ bias,
    const float* __restrict__ S,      // [64]
    float* __restrict__ out)          // [64][8192]
{
    const int e  = (blockIdx.x * 256 + threadIdx.x) * 4;
    const int m  = e >> 13;           // / 8192
    const int ch = e & (OC - 1);

    float4 s = {0.f, 0.f, 0.f, 0.f};
#pragma unroll
    for (int k = 0; k < KSPLIT; ++k) {
        const float4 p = *(const float4*)(part + (size_t)k * (BATCH * OC) + e);
        s.x += p.x; s.y += p.y; s.z += p.z; s.w += p.w;
    }
    const float4 d = *(const float4*)(delta + ch);
    const float4 z = *(const float4*)(zp + ch);
    const float4 b = *(const float4*)(bias + ch);
    const float Sm = S[m];

    float4 o;
    o.x = d.x * s.x + b.x - d.x * z.x * Sm;
    o.y = d.y * s.y + b.y - d.y * z.y * Sm;
    o.z = d.z * s.z + b.z - d.z * z.z * Sm;
    o.w = d.w * s.w + b.w - d.w * z.w * Sm;
    *(float4*)(out + e) = o;
}

extern "C" void kernel_launch(void* const* d_in, const int* in_sizes, int n_in,
                              void* d_out, int out_size, void* d_ws, size_t ws_size,
                              hipStream_t stream) {
    const float* input = (const float*)d_in[0];
    const int*   wpk   = (const int*)d_in[1];
    const float* delta = (const float*)d_in[2];
    const float* zp    = (const float*)d_in[3];
    const float* bias  = (const float*)d_in[4];
    float* out = (float*)d_out;

    // ws layout: Abf (1 MiB) | S (4 KiB slot) | partial (8 MiB)
    unsigned short* Abf = (unsigned short*)d_ws;
    float* S    = (float*)((char*)d_ws + (size_t)BATCH * IC * 2);
    float* part = (float*)((char*)d_ws + (size_t)BATCH * IC * 2 + 4096);

    prep_kernel<<<dim3(BATCH), dim3(256), 0, stream>>>(input, Abf, S);
    gemm_kernel<<<dim3(128 * KSPLIT), dim3(512), 0, stream>>>(Abf, wpk, part);
    reduce_kernel<<<dim3(BATCH * OC / 1024), dim3(256), 0, stream>>>(part, delta, zp, bias, S, out);
}

// Round 2
// 208.487 us; speedup vs baseline: 1.0031x; 1.0031x over previous
//
#include <hip/hip_runtime.h>

// Problem constants
constexpr int BATCH = 64;     // M
constexpr int IC    = 8192;   // K
constexpr int OC    = 8192;   // N
constexpr int OCH   = 4096;   // packed rows (OC/2)
constexpr int KSPLIT = 4;
constexpr int KPER  = IC / KSPLIT;   // 2048
constexpr int BK    = 128;           // K-chunk staged in LDS
constexpr int NITER = KPER / BK;     // 16
constexpr int LDK   = BK + 8;        // 136: keeps the conflict-free bank rotation

typedef __bf16 bf16x8 __attribute__((ext_vector_type(8)));
typedef float  f32x4  __attribute__((ext_vector_type(4)));
typedef int    i32x4  __attribute__((ext_vector_type(4)));

// fp32 -> bf16 round-to-nearest-even
static __device__ __forceinline__ unsigned short f2bf(float f) {
    unsigned u = __float_as_uint(f);
    u += 0x7FFFu + ((u >> 16) & 1u);
    return (unsigned short)(u >> 16);
}

// (bf16(n1)<<16) | bf16(n0) for small ints 0..15 (fp32 truncation exact)
static __device__ __forceinline__ unsigned pack2bf(int n0, int n1) {
    unsigned f0 = __float_as_uint((float)n0);
    unsigned f1 = __float_as_uint((float)n1);
    return __builtin_amdgcn_perm(f1, f0, 0x07060302u);
}

// ---------------------------------------------------------------------------
// Prep: input fp32 [64,8192] -> bf16 in ws, plus per-row partial sums
// S4[64][4] (summed by the reduce kernel). 256 blocks = quarter-row each.
// ---------------------------------------------------------------------------
__global__ __launch_bounds__(256) void prep_kernel(
    const float* __restrict__ in, unsigned short* __restrict__ Abf,
    float* __restrict__ S4)
{
    const int b   = blockIdx.x;        // 0..255
    const int row = b >> 2;
    const int q   = b & 3;
    const int t   = threadIdx.x;
    const float*          rp = in  + (size_t)row * IC + q * 2048;
    unsigned short*       op = Abf + (size_t)row * IC + q * 2048;

    float sum = 0.f;
#pragma unroll
    for (int i = 0; i < 2; ++i) {
        const int c = i * 1024 + t * 4;
        const float4 v = *(const float4*)(rp + c);
        sum += (v.x + v.y) + (v.z + v.w);
        ushort4 o = make_ushort4(f2bf(v.x), f2bf(v.y), f2bf(v.z), f2bf(v.w));
        *(ushort4*)(op + c) = o;
    }
#pragma unroll
    for (int off = 32; off > 0; off >>= 1) sum += __shfl_down(sum, off);

    __shared__ float red[4];
    if ((t & 63) == 0) red[t >> 6] = sum;
    __syncthreads();
    if (t == 0) S4[row * 4 + q] = (red[0] + red[1]) + (red[2] + red[3]);
}

// ---------------------------------------------------------------------------
// GEMM: partial[ks][64][8192] = A.Q^T over this split's K-range.
// 512 blocks (128 n-tiles x 4 k-splits) x 512 threads (8 waves, 2 blocks/CU).
// Tile M=64 x N=64; BK=128/iter; wave-quads split K halves (kh=0/1), LDS
// cross-reduce at the epilogue. Depth-2 register prefetch PLUS raw s_barrier
// with lgkmcnt-only wait: __syncthreads() would drain vmcnt(0) and kill the
// prefetch every iteration (the documented pre-barrier drain); the raw
// barrier keeps the just-issued global loads in flight across it, and the
// compiler's register-dep tracking emits a counted vmcnt before STAGE.
// Weight loads are non-temporal: streamed once, must not evict the A panel
// from L2 (A is re-read by 128 blocks per k-split).
// ---------------------------------------------------------------------------
__global__ __launch_bounds__(512, 4) void gemm_kernel(
    const unsigned short* __restrict__ Abf,   // bf16 [64][8192]
    const int* __restrict__ wp,               // packed [4096][8192]
    float* __restrict__ part)                 // fp32 [KSPLIT][64][8192]
{
    __shared__ unsigned short lA[2][64 * LDK];
    __shared__ unsigned short lW[2][64 * LDK];  // rows 0..31 lo nibble, 32..63 hi

    const int t    = threadIdx.x;
    const int lane = t & 63;
    const int lm   = lane & 15;
    const int lq   = lane >> 4;
    const int wv   = (t >> 6) & 3;   // column-wave 0..3
    const int kh   = t >> 8;         // K-half 0/1

    const int nt  = blockIdx.x & 127;
    const int ks  = blockIdx.x >> 7;
    const int r0  = nt * 32;
    const int kb0 = ks * KPER;

    f32x4 acc[4];
    const f32x4 zero4 = {0.f, 0.f, 0.f, 0.f};
#pragma unroll
    for (int i = 0; i < 4; ++i) acc[i] = zero4;

    // staging maps: A: 64 rows x 8 segs of 16 bf16; W: 32 rows x 16 segs of 8 ints
    const int uAr = t >> 3, uAc = (t & 7) * 16;
    const int uWr = t >> 4, uWc = (t & 15) * 8;

    const unsigned short* pA = Abf + (size_t)uAr * IC + kb0 + uAc;
    const int*            pW = wp  + (size_t)(r0 + uWr) * IC + kb0 + uWc;

    // LDS offsets (ushort units)
    const int sAo   = uAr * LDK + uAc;
    const int sWoLo = uWr * LDK + uWc;
    const int sWoHi = (uWr + 32) * LDK + uWc;
    const int fBo   = (wv * 16 + lm) * LDK + kh * 64 + lq * 8;
    const int fAo   = lm * LDK + kh * 64 + lq * 8;

    i32x4 aA0, aA1, wA0, wA1;   // register set A (even chunks)
    i32x4 aB0, aB1, wB0, wB1;   // register set B (odd chunks)

    // K-loop barrier: lgkmcnt-only (LDS reads into regs + LDS writes must be
    // done before crossing); vmcnt deliberately NOT drained.
#define KBAR() { asm volatile("s_waitcnt lgkmcnt(0)" ::: "memory"); \
                 __builtin_amdgcn_s_barrier(); }

#define LOADG(sa0, sa1, sw0, sw1, koff)                                  \
    sa0 = *(const i32x4*)(pA + (koff));                                  \
    sa1 = *(const i32x4*)(pA + (koff) + 8);                              \
    sw0 = __builtin_nontemporal_load((const i32x4*)(pW + (koff)));       \
    sw1 = __builtin_nontemporal_load((const i32x4*)(pW + (koff) + 4));

#define STAGE(buf, sa0, sa1, sw0, sw1) {             \
    *(i32x4*)(&lA[buf][sAo])     = sa0;              \
    *(i32x4*)(&lA[buf][sAo + 8]) = sa1;              \
    i32x4 lo_, hi_;                                  \
    lo_[0] = pack2bf(sw0[0] & 15, sw0[1] & 15);      \
    lo_[1] = pack2bf(sw0[2] & 15, sw0[3] & 15);      \
    lo_[2] = pack2bf(sw1[0] & 15, sw1[1] & 15);      \
    lo_[3] = pack2bf(sw1[2] & 15, sw1[3] & 15);      \
    hi_[0] = pack2bf(sw0[0] >> 4, sw0[1] >> 4);      \
    hi_[1] = pack2bf(sw0[2] >> 4, sw0[3] >> 4);      \
    hi_[2] = pack2bf(sw1[0] >> 4, sw1[1] >> 4);      \
    hi_[3] = pack2bf(sw1[2] >> 4, sw1[3] >> 4);      \
    *(i32x4*)(&lW[buf][sWoLo]) = lo_;                \
    *(i32x4*)(&lW[buf][sWoHi]) = hi_; }

#define MM(p) {                                                                   \
    _Pragma("unroll")                                                             \
    for (int s = 0; s < 2; ++s) {                                                 \
        const bf16x8 bfrg = *(const bf16x8*)(&lW[p][fBo + s * 32]);               \
        _Pragma("unroll")                                                         \
        for (int mt = 0; mt < 4; ++mt) {                                          \
            const bf16x8 afrg = *(const bf16x8*)(&lA[p][fAo + mt * 16 * LDK + s * 32]); \
            acc[mt] = __builtin_amdgcn_mfma_f32_16x16x32_bf16(afrg, bfrg, acc[mt], 0, 0, 0); \
        } } }

    // ---- prologue: chunks 0 and 1 in flight; stage chunk 0 ----
    LOADG(aA0, aA1, wA0, wA1, 0);
    LOADG(aB0, aB1, wB0, wB1, BK);
    STAGE(0, aA0, aA1, wA0, wA1);
    KBAR();

    // ---- main loop: 7 pairs covering it = 0..13; issues chunks 2..15 ----
    for (int it2 = 0; it2 < (NITER - 2) / 2; ++it2) {
        {   // even it: compute buf0 (chunk it), issue chunk it+2 -> setA,
            // stage chunk it+1 (setB, issued last iter) -> buf1
            const int koff = (2 * it2 + 2) * BK;
            LOADG(aA0, aA1, wA0, wA1, koff);
            MM(0);
            STAGE(1, aB0, aB1, wB0, wB1);
            KBAR();
        }
        {   // odd it: compute buf1, issue chunk it+2 -> setB,
            // stage chunk it+1 (setA, issued last iter) -> buf0
            const int koff = (2 * it2 + 3) * BK;
            LOADG(aB0, aB1, wB0, wB1, koff);
            MM(1);
            STAGE(0, aA0, aA1, wA0, wA1);
            KBAR();
        }
    }
    // it = NITER-2: compute buf0, stage chunk 15 (setB) -> buf1 (no issue)
    MM(0);
    STAGE(1, aB0, aB1, wB0, wB1);
    KBAR();
    // it = NITER-1: compute buf1
    MM(1);

#undef LOADG
#undef STAGE
#undef MM
#undef KBAR

    // ---- epilogue: cross-reduce kh halves via LDS, then store ----
    __syncthreads();                       // all LDS reads of lA/lW done
    f32x4* lR = (f32x4*)(&lA[0][0]);       // 16 KiB scratch
    const int o = (wv * 64 + lane) << 2;
    if (kh) {
#pragma unroll
        for (int mt = 0; mt < 4; ++mt) lR[o + mt] = acc[mt];
    }
    __syncthreads();
    if (!kh) {
#pragma unroll
        for (int mt = 0; mt < 4; ++mt) acc[mt] += lR[o + mt];

        // C/D layout: col(n) = lane&15, row(m within tile) = lq*4 + reg.
        const int cr = wv * 16 + lm;
        const int ch = (cr < 32) ? (r0 + cr) : (OCH + r0 + (cr - 32));
        float* pout = part + (size_t)ks * (BATCH * OC) + ch;

#pragma unroll
        for (int mt = 0; mt < 4; ++mt) {
#pragma unroll
            for (int r = 0; r < 4; ++r) {
                const int m = mt * 16 + lq * 4 + r;
                pout[(size_t)m * OC] = acc[mt][r];
            }
        }
    }
}

// ---------------------------------------------------------------------------
// Reduce: out[m][ch] = delta[ch]*dot + bias[ch] - delta[ch]*zp[ch]*S[m]
// Sums KSPLIT partials; fully overwrites d_out (no memset needed).
// ---------------------------------------------------------------------------
__global__ __launch_bounds__(256) void reduce_kernel(
    const float* __restrict__ part,   // [KSPLIT][64][8192]
    const float* __restrict__ delta,
    const float* __restrict__ zp,
    const float* __restrict__ bias,
    const float* __restrict__ S4,     // [64][4]
    float* __restrict__ out)          // [64][8192]
{
    const int e  = (blockIdx.x * 256 + threadIdx.x) * 4;
    const int m  = e >> 13;           // / 8192
    const int ch = e & (OC - 1);

    float4 s = {0.f, 0.f, 0.f, 0.f};
#pragma unroll
    for (int k = 0; k < KSPLIT; ++k) {
        const float4 p = *(const float4*)(part + (size_t)k * (BATCH * OC) + e);
        s.x += p.x; s.y += p.y; s.z += p.z; s.w += p.w;
    }
    const float4 d = *(const float4*)(delta + ch);
    const float4 z = *(const float4*)(zp + ch);
    const float4 b = *(const float4*)(bias + ch);
    const float Sm = (S4[m * 4 + 0] + S4[m * 4 + 1]) + (S4[m * 4 + 2] + S4[m * 4 + 3]);

    float4 o;
    o.x = d.x * s.x + b.x - d.x * z.x * Sm;
    o.y = d.y * s.y + b.y - d.y * z.y * Sm;
    o.z = d.z * s.z + b.z - d.z * z.z * Sm;
    o.w = d.w * s.w + b.w - d.w * z.w * Sm;
    *(float4*)(out + e) = o;
}

extern "C" void kernel_launch(void* const* d_in, const int* in_sizes, int n_in,
                              void* d_out, int out_size, void* d_ws, size_t ws_size,
                              hipStream_t stream) {
    const float* input = (const float*)d_in[0];
    const int*   wpk   = (const int*)d_in[1];
    const float* delta = (const float*)d_in[2];
    const float* zp    = (const float*)d_in[3];
    const float* bias  = (const float*)d_in[4];
    float* out = (float*)d_out;

    // ws layout: Abf (1 MiB) | S4 (4 KiB slot) | partial (8 MiB)
    unsigned short* Abf = (unsigned short*)d_ws;
    float* S4   = (float*)((char*)d_ws + (size_t)BATCH * IC * 2);
    float* part = (float*)((char*)d_ws + (size_t)BATCH * IC * 2 + 4096);

    prep_kernel<<<dim3(256), dim3(256), 0, stream>>>(input, Abf, S4);
    gemm_kernel<<<dim3(128 * KSPLIT), dim3(512), 0, stream>>>(Abf, wpk, part);
    reduce_kernel<<<dim3(BATCH * OC / 1024), dim3(256), 0, stream>>>(part, delta, zp, bias, S4, out);
}